// Round 21
// baseline (239.074 us; speedup 1.0000x reference)
//
#include <hip/hip_runtime.h>
#include <hip/hip_bf16.h>
#include <math.h>

typedef __bf16 bf16x8_t __attribute__((ext_vector_type(8)));
typedef float f32x4 __attribute__((ext_vector_type(4)));
typedef unsigned short ushort8 __attribute__((ext_vector_type(8)));

__device__ inline unsigned short f2bf(float f) {
  unsigned int u = __builtin_bit_cast(unsigned int, f);
  u += 0x7fffu + ((u >> 16) & 1u);
  return (unsigned short)(u >> 16);
}
__device__ inline float b2f(unsigned short s) {
  unsigned int u = ((unsigned int)s) << 16;
  return __builtin_bit_cast(float, u);
}
__device__ inline unsigned int pack2bf(float lo, float hi) {
  return (unsigned int)f2bf(lo) | ((unsigned int)f2bf(hi) << 16);
}

__device__ __forceinline__ void gll16(const void* g, void* l) {
  __builtin_amdgcn_global_load_lds((const __attribute__((address_space(1))) void*)g,
                                   (__attribute__((address_space(3))) void*)l, 16, 0, 0);
}

// ---------- unified prepass: all weight transposes+converts AND x fp32->bf16 convert ----------
__global__ __launch_bounds__(256) void prep_k(const float* __restrict__ x,
                                              const float* __restrict__ Wq,
                                              const float* __restrict__ Wk,
                                              const float* __restrict__ Wv,
                                              const float* __restrict__ Wo,
                                              unsigned short* __restrict__ xb,
                                              unsigned short* __restrict__ WallT,
                                              unsigned short* __restrict__ WoT) {
  const int bid = blockIdx.x;
  const int tid = threadIdx.x;
  if (bid < 10240) {
    __shared__ float tile[32][33];
    const int K = 2048;
    int y = bid / 64;
    int k0 = (bid % 64) * 32;
    const float* W;
    unsigned short* dst;
    int srcN, col0, dstRow0;
    if (y < 64) { W = Wq; srcN = 2048; col0 = y * 32; dst = WallT; dstRow0 = y * 32; }
    else if (y < 80) { W = Wk; srcN = 512; col0 = (y - 64) * 32; dst = WallT; dstRow0 = 2048 + (y - 64) * 32; }
    else if (y < 96) { W = Wv; srcN = 512; col0 = (y - 80) * 32; dst = WallT; dstRow0 = 2560 + (y - 80) * 32; }
    else { W = Wo; srcN = 2048; col0 = (y - 96) * 32; dst = WoT; dstRow0 = (y - 96) * 32; }
    int tx = tid & 31, ty = tid >> 5;  // 32 x 8
#pragma unroll
    for (int i = 0; i < 32; i += 8) tile[ty + i][tx] = W[(size_t)(k0 + ty + i) * srcN + col0 + tx];
    __syncthreads();
#pragma unroll
    for (int i = 0; i < 32; i += 8)
      dst[(size_t)(dstRow0 + ty + i) * K + k0 + tx] = f2bf(tile[tx][ty + i]);
  } else {
    int i = (bid - 10240) * 256 + tid;
    const float4* p = (const float4*)x + 2 * (size_t)i;
    float4 a = p[0], b = p[1];
    ushort8 v;
    v[0] = f2bf(a.x); v[1] = f2bf(a.y); v[2] = f2bf(a.z); v[3] = f2bf(a.w);
    v[4] = f2bf(b.x); v[5] = f2bf(b.y); v[6] = f2bf(b.z); v[7] = f2bf(b.w);
    ((ushort8*)xb)[i] = v;
  }
}

// ---------- 2-phase pipelined GEMM: C[M][N] = A[M][K] @ Bt[N][K]^T, fused RoPE, XCD swizzle ----------
template <bool OUT_BF16, bool ROPE>
__global__ __launch_bounds__(256) void gemm_tn(const unsigned short* __restrict__ A,
                                               const unsigned short* __restrict__ Bt,
                                               void* __restrict__ Cv, int M, int N, int K,
                                               const float* __restrict__ cs,
                                               const float* __restrict__ sn, int ropeLim) {
  __shared__ __align__(16) unsigned short As[2][128 * 32];
  __shared__ __align__(16) unsigned short Bs[2][128 * 32];
  const int t = threadIdx.x, w = t >> 6, lane = t & 63;
  const int la = lane & 15, lk = lane >> 4;
  const int wr = w >> 1, wc = w & 1;
  const int nwg = gridDim.x * gridDim.y;
  const int flat = blockIdx.y * gridDim.x + blockIdx.x;
  const int swz = (flat & 7) * (nwg >> 3) + (flat >> 3);
  const int bxs = swz % gridDim.x, bys = swz / gridDim.x;
  const int bm = bys * 128, bn = bxs * 128;
  const int lrow = lane >> 2, lcb = (lane & 3) * 8;

  const unsigned short* Ab = A + (size_t)(bm + (w * 2) * 16 + lrow) * K + lcb;
  const unsigned short* Ab1 = A + (size_t)(bm + (w * 2 + 1) * 16 + lrow) * K + lcb;
  const unsigned short* Bb = Bt + (size_t)(bn + (w * 2) * 16 + lrow) * K + lcb;
  const unsigned short* Bb1 = Bt + (size_t)(bn + (w * 2 + 1) * 16 + lrow) * K + lcb;
  const int c0 = w * 2, c1 = w * 2 + 1;

  f32x4 acc[4][4] = {};

  gll16(Ab, (char*)As[0] + c0 * 1024);
  gll16(Ab1, (char*)As[0] + c1 * 1024);
  gll16(Bb, (char*)Bs[0] + c0 * 1024);
  gll16(Bb1, (char*)Bs[0] + c1 * 1024);

  const int nt = K / 32;
  int cur = 0;
  for (int kt = 0; kt < nt; ++kt) {
    __syncthreads();
    if (kt + 1 < nt) {
      const int kn = (kt + 1) * 32;
      gll16(Ab + kn, (char*)As[cur ^ 1] + c0 * 1024);
      gll16(Ab1 + kn, (char*)As[cur ^ 1] + c1 * 1024);
      gll16(Bb + kn, (char*)Bs[cur ^ 1] + c0 * 1024);
      gll16(Bb1 + kn, (char*)Bs[cur ^ 1] + c1 * 1024);
    }

    bf16x8_t a[4], b[4];
#pragma unroll
    for (int m = 0; m < 4; ++m)
      a[m] = __builtin_bit_cast(
          bf16x8_t, *(const ushort8*)(As[cur] + (wr * 64 + m * 16 + la) * 32 + lk * 8));
#pragma unroll
    for (int n = 0; n < 4; ++n)
      b[n] = __builtin_bit_cast(
          bf16x8_t, *(const ushort8*)(Bs[cur] + (wc * 64 + n * 16 + la) * 32 + lk * 8));
#pragma unroll
    for (int m = 0; m < 4; ++m)
#pragma unroll
      for (int n = 0; n < 4; ++n)
        acc[m][n] = __builtin_amdgcn_mfma_f32_16x16x32_bf16(a[m], b[n], acc[m][n], 0, 0, 0);
    cur ^= 1;
  }

#pragma unroll
  for (int m = 0; m < 4; ++m) {
#pragma unroll
    for (int n = 0; n < 4; ++n) {
      const int col = bn + wc * 64 + n * 16 + la;
      const bool doRope = ROPE && (col < ropeLim);
#pragma unroll
      for (int r = 0; r < 4; ++r) {
        int row = bm + wr * 64 + m * 16 + lk * 4 + r;
        float val = acc[m][n][r];
        if (ROPE) {
          float pval = __shfl_xor(val, 1);
          if (doRope) {
            int srow = row & 2047;
            int i = (col & 127) >> 1;
            float cc = cs[srow * 64 + i], ss = sn[srow * 64 + i];
            val = (la & 1) ? (pval * ss + val * cc) : (val * cc - pval * ss);
          }
        }
        if (OUT_BF16)
          ((unsigned short*)Cv)[(size_t)row * N + col] = f2bf(val);
        else
          ((float*)Cv)[(size_t)row * N + col] = val;
      }
    }
  }
}

// ---------- V transpose: Vt[(b*4+g)*128 + d][s] = QKV[(b*2048+s)*3072 + 2560 + g*128 + d] ----------
__global__ void transpose_v(const unsigned short* __restrict__ QKV, unsigned short* __restrict__ Vt) {
  __shared__ unsigned short tile[32][33];
  int bg = blockIdx.z;
  int b = bg >> 2, g = bg & 3;
  int s0 = blockIdx.x * 32, d0 = blockIdx.y * 32;
  int tx = threadIdx.x, ty = threadIdx.y;  // 32 x 8
#pragma unroll
  for (int i = 0; i < 32; i += 8)
    tile[ty + i][tx] = QKV[((size_t)(b * 2048 + s0 + ty + i)) * 3072 + 2560 + g * 128 + d0 + tx];
  __syncthreads();
#pragma unroll
  for (int i = 0; i < 32; i += 8)
    Vt[((size_t)(bg * 128 + d0 + ty + i)) * 2048 + s0 + tx] = tile[tx][ty + i];
}

// ---------- MFMA flash attention: high-TLP variant ----------
// 4 waves x 16 q-rows, q-tile 64, kv-tile 32, LDS 36 KB -> 4 blocks/CU, grid 1024 blocks.
// Swapped QK^T, packed-P LDS (64B rows), gll16 double-buffer, 4-way qt balance, defer-max.
// grid (32, 16 heads, B), block 256.
__global__ __launch_bounds__(256, 4) void attn_mfma(const unsigned short* __restrict__ QKV,
                                                    const unsigned short* __restrict__ Vt,
                                                    unsigned short* __restrict__ Ob) {
  const int S = 2048;
  __shared__ __align__(16) unsigned short Ks[2][32 * 128];  // 8 KB each, linear, pre-swizzled
  __shared__ __align__(16) unsigned short Vs[2][128 * 32];  // 8 KB each, linear, pre-swizzled
  __shared__ __align__(16) unsigned short Ps[4 * 16 * 32];  // 4 KB, per-wave packed P

  const int t = threadIdx.x;
  const int w = t >> 6, lane = t & 63;
  const int la = lane & 15, lk = lane >> 4;
  const int b = blockIdx.z, h = blockIdx.y, g = h >> 2;
  // 4-way qt balance: the 4 blocks co-resident on a CU (x, h>>3, b combos) get qt summing to 62
  const int x = blockIdx.x;
  const int hb = ((h >> 3) & 1) | ((b & 1) << 1);
  int qt;
  if (hb == 0) qt = x;
  else if (hb == 1) qt = 31 - x;
  else if (hb == 2) qt = (x + 16) & 31;
  else qt = 31 - ((x + 16) & 31);
  const int qw = qt * 64 + w * 16;
  const float scale = 0.08838834764831845f;  // 1/sqrt(128)

  // staging: wave w stages K groups {2w,2w+1} (4 rows x 16 chunks) and V groups (16 rows x 4 chunks)
  // pre-swizzled GLOBAL source, linear LDS dest
  const unsigned short* ksrc[2];
  const unsigned short* vsrc[2];
#pragma unroll
  for (int u = 0; u < 2; ++u) {
    int kr = (2 * w + u) * 4 + (lane >> 4);
    int kp = lane & 15;
    ksrc[u] = QKV + (size_t)(b * S + kr) * 3072 + 2048 + g * 128 + (kp ^ (kr & 7)) * 8;
    int vr = (2 * w + u) * 16 + (lane >> 2);
    int vp = lane & 3;
    vsrc[u] = Vt + (size_t)((b * 4 + g) * 128 + vr) * 2048 + (vp ^ (vr & 3)) * 8;
  }

  // Q fragments: q-row = qw + la, d = dt*32 + lk*8 + i
  bf16x8_t qf[4];
#pragma unroll
  for (int dt = 0; dt < 4; ++dt)
    qf[dt] = __builtin_bit_cast(
        bf16x8_t,
        *(const ushort8*)(QKV + (size_t)(b * S + qw + la) * 3072 + h * 128 + dt * 32 + lk * 8));

  f32x4 oa[8];
#pragma unroll
  for (int dt = 0; dt < 8; ++dt) oa[dt] = (f32x4){0.f, 0.f, 0.f, 0.f};
  float mr = -1e30f, lr = 0.f;

  const int n_kt = 2 * qt + 2;        // kv tiles of 32 covering q0..q0+63 (block-uniform)
  const int kmask0 = qw & ~31;        // single partially-masked kv tile for this wave
  char* pw = (char*)Ps + w * 1024;

  // prologue: stage tile 0 into buf 0
#pragma unroll
  for (int u = 0; u < 2; ++u) {
    gll16(ksrc[u], (char*)Ks[0] + (2 * w + u) * 1024);
    gll16(vsrc[u], (char*)Vs[0] + (2 * w + u) * 1024);
  }
  __syncthreads();

  int cur = 0;
  for (int kt = 0; kt < n_kt; ++kt) {
    const int k0 = kt * 32;
    // prefetch next tile into the other buffer
    if (kt + 1 < n_kt) {
      const int kn = k0 + 32;
#pragma unroll
      for (int u = 0; u < 2; ++u) {
        gll16(ksrc[u] + (size_t)kn * 3072, (char*)Ks[cur ^ 1] + (2 * w + u) * 1024);
        gll16(vsrc[u] + kn, (char*)Vs[cur ^ 1] + (2 * w + u) * 1024);
      }
    }

    if (k0 <= qw + 15) {  // wave not fully masked
      char* Ksb = (char*)Ks[cur];
      char* Vsb = (char*)Vs[cur];

      // swapped QK^T: sacc[ktc]: row = kv (ktc*16 + lk*4 + r), col = q (la)
      f32x4 sacc[2];
#pragma unroll
      for (int ktc = 0; ktc < 2; ++ktc) sacc[ktc] = (f32x4){0.f, 0.f, 0.f, 0.f};
      __builtin_amdgcn_s_setprio(1);
#pragma unroll
      for (int ktc = 0; ktc < 2; ++ktc) {
        int row = ktc * 16 + la;
#pragma unroll
        for (int dt = 0; dt < 4; ++dt) {
          bf16x8_t kf = __builtin_bit_cast(
              bf16x8_t, *(const ushort8*)(Ksb + row * 256 + ((((dt << 2) + lk) ^ (row & 7)) << 4)));
          sacc[ktc] = __builtin_amdgcn_mfma_f32_16x16x32_bf16(kf, qf[dt], sacc[ktc], 0, 0, 0);
        }
      }
      __builtin_amdgcn_s_setprio(0);

      const bool domask = (k0 == kmask0);
      const int q = qw + la;  // this lane's softmax row
      float p[2][4];
      float tm = -1e30f;
#pragma unroll
      for (int ktc = 0; ktc < 2; ++ktc)
#pragma unroll
        for (int r = 0; r < 4; ++r) {
          float sv = sacc[ktc][r] * scale;
          if (domask && (k0 + ktc * 16 + lk * 4 + r > q)) sv = -1e30f;
          p[ktc][r] = sv;
          tm = fmaxf(tm, sv);
        }
      tm = fmaxf(tm, __shfl_xor(tm, 16));
      tm = fmaxf(tm, __shfl_xor(tm, 32));
      // defer-max (T13)
      float mn;
      if (__all(tm - mr <= 8.f)) {
        mn = mr;
      } else {
        mn = fmaxf(mr, tm);
        float sc = __expf(mr - mn);
        mr = mn;
        lr *= sc;
        float scb[4];
#pragma unroll
        for (int r = 0; r < 4; ++r) scb[r] = __shfl(sc, lk * 4 + r);
#pragma unroll
        for (int dt = 0; dt < 8; ++dt)
#pragma unroll
          for (int r = 0; r < 4; ++r) oa[dt][r] *= scb[r];
      }
      float ts = 0.f;
#pragma unroll
      for (int ktc = 0; ktc < 2; ++ktc)
#pragma unroll
        for (int r = 0; r < 4; ++r) {
          float e = __expf(p[ktc][r] - mn);
          p[ktc][r] = e;
          ts += e;
        }
      ts += __shfl_xor(ts, 16);
      ts += __shfl_xor(ts, 32);
      lr += ts;
      // packed P write: row q=la (64B), 16B-chunk c = ktc*2+(lk>>1), sub (lk&1)*8, XOR (la&3)
      char* pq = pw + la * 64;
#pragma unroll
      for (int ktc = 0; ktc < 2; ++ktc) {
        uint2 gv;
        gv.x = pack2bf(p[ktc][0], p[ktc][1]);
        gv.y = pack2bf(p[ktc][2], p[ktc][3]);
        *(uint2*)(pq + (((ktc * 2 + (lk >> 1)) ^ (la & 3)) << 4) + ((lk & 1) << 3)) = gv;
      }
      asm volatile("s_waitcnt lgkmcnt(0)" ::: "memory");

      // P fragment: P[q=la][kv = lk*8..+7] -> chunk lk, XOR (la&3)
      bf16x8_t pf = __builtin_bit_cast(
          bf16x8_t, *(const ushort8*)(pw + la * 64 + ((lk ^ (la & 3)) << 4)));
      __builtin_amdgcn_s_setprio(1);
#pragma unroll
      for (int dt = 0; dt < 8; ++dt) {
        int d = dt * 16 + la;
        bf16x8_t vf = __builtin_bit_cast(
            bf16x8_t, *(const ushort8*)(Vsb + d * 64 + ((lk ^ (d & 3)) << 4)));
        oa[dt] = __builtin_amdgcn_mfma_f32_16x16x32_bf16(pf, vf, oa[dt], 0, 0, 0);
      }
      __builtin_amdgcn_s_setprio(0);
    }

    __syncthreads();  // prefetched tile landed; all reads of cur done
    cur ^= 1;
  }

  float inv = 1.f / lr;
  float invb[4];
#pragma unroll
  for (int r = 0; r < 4; ++r) invb[r] = __shfl(inv, lk * 4 + r);
#pragma unroll
  for (int dt = 0; dt < 8; ++dt)
#pragma unroll
    for (int r = 0; r < 4; ++r)
      Ob[(size_t)(b * S + qw + lk * 4 + r) * 2048 + h * 128 + dt * 16 + la] =
          f2bf(oa[dt][r] * invb[r]);
}

extern "C" void kernel_launch(void* const* d_in, const int* in_sizes, int n_in,
                              void* d_out, int out_size, void* d_ws, size_t ws_size,
                              hipStream_t stream) {
  const float* x = (const float*)d_in[0];
  const float* rc = (const float*)d_in[1];
  const float* rs = (const float*)d_in[2];
  const float* Wq = (const float*)d_in[3];
  const float* Wk = (const float*)d_in[4];
  const float* Wv = (const float*)d_in[5];
  const float* Wo = (const float*)d_in[6];
  float* out = (float*)d_out;

  const int B = 2, S = 2048, DM = 2048;
  const int M = B * S;  // 4096

  // workspace (bf16 elems): xb | QKV | WallT | WoT | (Vt in dead WallT rows)
  unsigned short* xb = (unsigned short*)d_ws;              // M x 2048      (16 MB)
  unsigned short* QKV = xb + (size_t)M * DM;               // M x 3072      (25.2 MB)
  unsigned short* WallT = QKV + (size_t)M * 3072;          // 3072 x 2048   (12.6 MB)
  unsigned short* WoT = WallT + (size_t)3072 * DM;         // 2048 x 2048   (8.4 MB)
  unsigned short* Vt = WallT + (size_t)2048 * 2048;        // 1024 x 2048 (4 MB, dead Wk/Wv rows)
  unsigned short* Ob = xb;                                 // alias (x dead after proj)

  dim3 blk(256);

  // unified prepass: weight transposes + x convert in one launch
  prep_k<<<dim3(14336), blk, 0, stream>>>(x, Wq, Wk, Wv, Wo, xb, WallT, WoT);

  // fused QKV projection + RoPE on cols < 2560 (Q and K regions)
  gemm_tn<true, true><<<dim3(3072 / 128, M / 128), blk, 0, stream>>>(xb, WallT, QKV, M, 3072, DM,
                                                                     rc, rs, 2560);

  transpose_v<<<dim3(S / 32, 4, B * 4), dim3(32, 8), 0, stream>>>(QKV, Vt);

  attn_mfma<<<dim3(32, 16, B), dim3(256), 0, stream>>>(QKV, Vt, Ob);

  gemm_tn<false, false><<<dim3(DM / 128, M / 128), blk, 0, stream>>>(Ob, WoT, out, M, DM, DM,
                                                                     nullptr, nullptr, 0);
}

// Round 22
// 225.821 us; speedup vs baseline: 1.0587x; 1.0587x over previous
//
#include <hip/hip_runtime.h>
#include <hip/hip_bf16.h>
#include <math.h>

typedef __bf16 bf16x8_t __attribute__((ext_vector_type(8)));
typedef float f32x4 __attribute__((ext_vector_type(4)));
typedef unsigned short ushort8 __attribute__((ext_vector_type(8)));

__device__ inline unsigned short f2bf(float f) {
  unsigned int u = __builtin_bit_cast(unsigned int, f);
  u += 0x7fffu + ((u >> 16) & 1u);
  return (unsigned short)(u >> 16);
}
__device__ inline float b2f(unsigned short s) {
  unsigned int u = ((unsigned int)s) << 16;
  return __builtin_bit_cast(float, u);
}
__device__ inline unsigned int pack2bf(float lo, float hi) {
  return (unsigned int)f2bf(lo) | ((unsigned int)f2bf(hi) << 16);
}

__device__ __forceinline__ void gll16(const void* g, void* l) {
  __builtin_amdgcn_global_load_lds((const __attribute__((address_space(1))) void*)g,
                                   (__attribute__((address_space(3))) void*)l, 16, 0, 0);
}

// ---------- unified prepass: all weight transposes+converts AND x fp32->bf16 convert ----------
// blocks [0, 10240): weight transpose tiles; y = bid/64 in [0,160), k-block = bid%64
//   y in [0,64):   Wq col y*32      -> WallT row y*32
//   y in [64,80):  Wk col (y-64)*32 -> WallT row 2048+(y-64)*32
//   y in [80,96):  Wv col (y-80)*32 -> WallT row 2560+(y-80)*32
//   y in [96,160): Wo col (y-96)*32 -> WoT   row (y-96)*32
// blocks [10240, 14336): x convert, i = (bid-10240)*256 + tid over M*DM/8 ushort8 elements
__global__ __launch_bounds__(256) void prep_k(const float* __restrict__ x,
                                              const float* __restrict__ Wq,
                                              const float* __restrict__ Wk,
                                              const float* __restrict__ Wv,
                                              const float* __restrict__ Wo,
                                              unsigned short* __restrict__ xb,
                                              unsigned short* __restrict__ WallT,
                                              unsigned short* __restrict__ WoT) {
  const int bid = blockIdx.x;
  const int tid = threadIdx.x;
  if (bid < 10240) {
    __shared__ float tile[32][33];
    const int K = 2048;
    int y = bid / 64;
    int k0 = (bid % 64) * 32;
    const float* W;
    unsigned short* dst;
    int srcN, col0, dstRow0;
    if (y < 64) { W = Wq; srcN = 2048; col0 = y * 32; dst = WallT; dstRow0 = y * 32; }
    else if (y < 80) { W = Wk; srcN = 512; col0 = (y - 64) * 32; dst = WallT; dstRow0 = 2048 + (y - 64) * 32; }
    else if (y < 96) { W = Wv; srcN = 512; col0 = (y - 80) * 32; dst = WallT; dstRow0 = 2560 + (y - 80) * 32; }
    else { W = Wo; srcN = 2048; col0 = (y - 96) * 32; dst = WoT; dstRow0 = (y - 96) * 32; }
    int tx = tid & 31, ty = tid >> 5;  // 32 x 8
#pragma unroll
    for (int i = 0; i < 32; i += 8) tile[ty + i][tx] = W[(size_t)(k0 + ty + i) * srcN + col0 + tx];
    __syncthreads();
#pragma unroll
    for (int i = 0; i < 32; i += 8)
      dst[(size_t)(dstRow0 + ty + i) * K + k0 + tx] = f2bf(tile[tx][ty + i]);
  } else {
    int i = (bid - 10240) * 256 + tid;  // < 4096*256 = M*DM/8 exactly
    const float4* p = (const float4*)x + 2 * (size_t)i;
    float4 a = p[0], b = p[1];
    ushort8 v;
    v[0] = f2bf(a.x); v[1] = f2bf(a.y); v[2] = f2bf(a.z); v[3] = f2bf(a.w);
    v[4] = f2bf(b.x); v[5] = f2bf(b.y); v[6] = f2bf(b.z); v[7] = f2bf(b.w);
    ((ushort8*)xb)[i] = v;
  }
}

// ---------- 2-phase pipelined GEMM: C[M][N] = A[M][K] @ Bt[N][K]^T, fused RoPE, XCD swizzle ----------
template <bool OUT_BF16, bool ROPE>
__global__ __launch_bounds__(256) void gemm_tn(const unsigned short* __restrict__ A,
                                               const unsigned short* __restrict__ Bt,
                                               void* __restrict__ Cv, int M, int N, int K,
                                               const float* __restrict__ cs,
                                               const float* __restrict__ sn, int ropeLim) {
  __shared__ __align__(16) unsigned short As[2][128 * 32];
  __shared__ __align__(16) unsigned short Bs[2][128 * 32];
  const int t = threadIdx.x, w = t >> 6, lane = t & 63;
  const int la = lane & 15, lk = lane >> 4;
  const int wr = w >> 1, wc = w & 1;
  const int nwg = gridDim.x * gridDim.y;
  const int flat = blockIdx.y * gridDim.x + blockIdx.x;
  const int swz = (flat & 7) * (nwg >> 3) + (flat >> 3);
  const int bxs = swz % gridDim.x, bys = swz / gridDim.x;
  const int bm = bys * 128, bn = bxs * 128;
  const int lrow = lane >> 2, lcb = (lane & 3) * 8;

  const unsigned short* Ab = A + (size_t)(bm + (w * 2) * 16 + lrow) * K + lcb;
  const unsigned short* Ab1 = A + (size_t)(bm + (w * 2 + 1) * 16 + lrow) * K + lcb;
  const unsigned short* Bb = Bt + (size_t)(bn + (w * 2) * 16 + lrow) * K + lcb;
  const unsigned short* Bb1 = Bt + (size_t)(bn + (w * 2 + 1) * 16 + lrow) * K + lcb;
  const int c0 = w * 2, c1 = w * 2 + 1;

  f32x4 acc[4][4] = {};

  gll16(Ab, (char*)As[0] + c0 * 1024);
  gll16(Ab1, (char*)As[0] + c1 * 1024);
  gll16(Bb, (char*)Bs[0] + c0 * 1024);
  gll16(Bb1, (char*)Bs[0] + c1 * 1024);

  const int nt = K / 32;
  int cur = 0;
  for (int kt = 0; kt < nt; ++kt) {
    __syncthreads();  // drains gll16 (buf[cur] ready); prior reads of buf[cur^1] done
    if (kt + 1 < nt) {
      const int kn = (kt + 1) * 32;
      gll16(Ab + kn, (char*)As[cur ^ 1] + c0 * 1024);
      gll16(Ab1 + kn, (char*)As[cur ^ 1] + c1 * 1024);
      gll16(Bb + kn, (char*)Bs[cur ^ 1] + c0 * 1024);
      gll16(Bb1 + kn, (char*)Bs[cur ^ 1] + c1 * 1024);
    }

    bf16x8_t a[4], b[4];
#pragma unroll
    for (int m = 0; m < 4; ++m)
      a[m] = __builtin_bit_cast(
          bf16x8_t, *(const ushort8*)(As[cur] + (wr * 64 + m * 16 + la) * 32 + lk * 8));
#pragma unroll
    for (int n = 0; n < 4; ++n)
      b[n] = __builtin_bit_cast(
          bf16x8_t, *(const ushort8*)(Bs[cur] + (wc * 64 + n * 16 + la) * 32 + lk * 8));
#pragma unroll
    for (int m = 0; m < 4; ++m)
#pragma unroll
      for (int n = 0; n < 4; ++n)
        acc[m][n] = __builtin_amdgcn_mfma_f32_16x16x32_bf16(a[m], b[n], acc[m][n], 0, 0, 0);
    cur ^= 1;
  }

#pragma unroll
  for (int m = 0; m < 4; ++m) {
#pragma unroll
    for (int n = 0; n < 4; ++n) {
      const int col = bn + wc * 64 + n * 16 + la;
      const bool doRope = ROPE && (col < ropeLim);  // uniform per block (ropeLim % 128 == 0)
#pragma unroll
      for (int r = 0; r < 4; ++r) {
        int row = bm + wr * 64 + m * 16 + lk * 4 + r;
        float val = acc[m][n][r];
        if (ROPE) {
          float pval = __shfl_xor(val, 1);  // partner column (col ^ 1), same row
          if (doRope) {
            int srow = row & 2047;
            int i = (col & 127) >> 1;
            float cc = cs[srow * 64 + i], ss = sn[srow * 64 + i];
            val = (la & 1) ? (pval * ss + val * cc) : (val * cc - pval * ss);
          }
        }
        if (OUT_BF16)
          ((unsigned short*)Cv)[(size_t)row * N + col] = f2bf(val);
        else
          ((float*)Cv)[(size_t)row * N + col] = val;
      }
    }
  }
}

// ---------- V transpose: Vt[(b*4+g)*128 + d][s] = QKV[(b*2048+s)*3072 + 2560 + g*128 + d] ----------
__global__ void transpose_v(const unsigned short* __restrict__ QKV, unsigned short* __restrict__ Vt) {
  __shared__ unsigned short tile[32][33];
  int bg = blockIdx.z;
  int b = bg >> 2, g = bg & 3;
  int s0 = blockIdx.x * 32, d0 = blockIdx.y * 32;
  int tx = threadIdx.x, ty = threadIdx.y;  // 32 x 8
#pragma unroll
  for (int i = 0; i < 32; i += 8)
    tile[ty + i][tx] = QKV[((size_t)(b * 2048 + s0 + ty + i)) * 3072 + 2560 + g * 128 + d0 + tx];
  __syncthreads();
#pragma unroll
  for (int i = 0; i < 32; i += 8)
    Vt[((size_t)(bg * 128 + d0 + ty + i)) * 2048 + s0 + tx] = tile[tx][ty + i];
}

// ---------- MFMA flash attention (R14 structure — measured best, 95 us) ----------
// 4 waves x 32 q-rows (2 subtiles), kv-tile 64, swapped QK^T, packed-P LDS,
// gll16 double-buffer pipeline, heavy+light qt pairing, defer-max.
// grid (S/128, 16 heads, B), block 256.
__global__ __launch_bounds__(256, 2) void attn_mfma(const unsigned short* __restrict__ QKV,
                                                    const unsigned short* __restrict__ Vt,
                                                    unsigned short* __restrict__ Ob) {
  const int S = 2048;
  __shared__ __align__(16) unsigned short Ks[2][64 * 128];   // linear [krow][d], pre-swizzled
  __shared__ __align__(16) unsigned short Vs[2][128 * 64];   // linear [d][kv], pre-swizzled
  __shared__ __align__(16) unsigned short Ps[4 * 32 * 64];   // per-wave packed P

  const int t = threadIdx.x;
  const int w = t >> 6, lane = t & 63;
  const int la = lane & 15, lk = lane >> 4;
  const int b = blockIdx.z, h = blockIdx.y, g = h >> 2;
  // heavy+light pairing: blocks i and i+256 (same CU under round-robin) get qt summing to 15
  const int qt = (b == 0) ? (gridDim.x - 1 - blockIdx.x) : blockIdx.x;
  const int q0 = qt * 128;
  const int qw = q0 + w * 32;
  const float scale = 0.08838834764831845f;  // 1/sqrt(128)

  // staging: wave w stages K groups 4w..4w+3 (4 rows x 16 chunks) and V groups (8 rows x 8 chunks)
  const unsigned short* ksrc[4];
  const unsigned short* vsrc[4];
#pragma unroll
  for (int u = 0; u < 4; ++u) {
    int kr = 16 * w + 4 * u + (lane >> 4);
    int kp = lane & 15;
    ksrc[u] = QKV + (size_t)(b * S + kr) * 3072 + 2048 + g * 128 + (kp ^ (kr & 7)) * 8;
    int vr = 32 * w + 8 * u + (lane >> 3);
    int vp = lane & 7;
    vsrc[u] = Vt + (size_t)((b * 4 + g) * 128 + vr) * 2048 + (vp ^ (vr & 7)) * 8;
  }

  // Q fragments: qf[qi][dt] at q-row = qw + qi*16 + la, d = dt*32 + lk*8 + i
  bf16x8_t qf[2][4];
#pragma unroll
  for (int qi = 0; qi < 2; ++qi)
#pragma unroll
    for (int dt = 0; dt < 4; ++dt)
      qf[qi][dt] = __builtin_bit_cast(
          bf16x8_t, *(const ushort8*)(QKV + (size_t)(b * S + qw + qi * 16 + la) * 3072 + h * 128 +
                                      dt * 32 + lk * 8));

  f32x4 oa[2][8];
#pragma unroll
  for (int qi = 0; qi < 2; ++qi)
#pragma unroll
    for (int dt = 0; dt < 8; ++dt) oa[qi][dt] = (f32x4){0.f, 0.f, 0.f, 0.f};
  float mr[2] = {-1e30f, -1e30f}, lr[2] = {0.f, 0.f};

  const int n_kt = 2 * qt + 2;
  const int kmask0 = qw & ~63;  // the single partially-masked kv tile for this wave
  char* pw = (char*)Ps + w * 4096;

  // prologue: stage tile 0 into buf 0
#pragma unroll
  for (int u = 0; u < 4; ++u) {
    gll16(ksrc[u], (char*)Ks[0] + (4 * w + u) * 1024);
    gll16(vsrc[u], (char*)Vs[0] + (4 * w + u) * 1024);
  }
  __syncthreads();

  int cur = 0;
  for (int kt = 0; kt < n_kt; ++kt) {
    const int k0 = kt * 64;
    // prefetch next tile into the other buffer
    if (kt + 1 < n_kt) {
      const int kn = k0 + 64;
#pragma unroll
      for (int u = 0; u < 4; ++u) {
        gll16(ksrc[u] + (size_t)kn * 3072, (char*)Ks[cur ^ 1] + (4 * w + u) * 1024);
        gll16(vsrc[u] + kn, (char*)Vs[cur ^ 1] + (4 * w + u) * 1024);
      }
    }

    if (k0 <= qw + 31) {  // wave not fully masked
      char* Ksb = (char*)Ks[cur];
      char* Vsb = (char*)Vs[cur];

      // swapped QK^T: sacc[qi][ktc] = S^T tile: row = kv (lk*4+r within ktc), col = q (la)
      f32x4 sacc[2][4];
#pragma unroll
      for (int qi = 0; qi < 2; ++qi)
#pragma unroll
        for (int ktc = 0; ktc < 4; ++ktc) sacc[qi][ktc] = (f32x4){0.f, 0.f, 0.f, 0.f};
      __builtin_amdgcn_s_setprio(1);
#pragma unroll
      for (int ktc = 0; ktc < 4; ++ktc) {
        int row = ktc * 16 + la;
#pragma unroll
        for (int dt = 0; dt < 4; ++dt) {
          bf16x8_t kf = __builtin_bit_cast(
              bf16x8_t, *(const ushort8*)(Ksb + row * 256 + ((((dt << 2) + lk) ^ (row & 7)) << 4)));
          sacc[0][ktc] = __builtin_amdgcn_mfma_f32_16x16x32_bf16(kf, qf[0][dt], sacc[0][ktc], 0, 0, 0);
          sacc[1][ktc] = __builtin_amdgcn_mfma_f32_16x16x32_bf16(kf, qf[1][dt], sacc[1][ktc], 0, 0, 0);
        }
      }
      __builtin_amdgcn_s_setprio(0);

      const bool domask = (k0 == kmask0);
#pragma unroll
      for (int qi = 0; qi < 2; ++qi) {
        const int q = qw + qi * 16 + la;  // this lane's softmax row
        float p[4][4];
        float tm = -1e30f;
#pragma unroll
        for (int ktc = 0; ktc < 4; ++ktc)
#pragma unroll
          for (int r = 0; r < 4; ++r) {
            float sv = sacc[qi][ktc][r] * scale;
            if (domask && (k0 + ktc * 16 + lk * 4 + r > q)) sv = -1e30f;
            p[ktc][r] = sv;
            tm = fmaxf(tm, sv);
          }
        tm = fmaxf(tm, __shfl_xor(tm, 16));
        tm = fmaxf(tm, __shfl_xor(tm, 32));
        // defer-max (T13): skip rescale when tile max growth is small
        float mn;
        if (__all(tm - mr[qi] <= 8.f)) {
          mn = mr[qi];  // keep old max; P bounded by e^8
        } else {
          mn = fmaxf(mr[qi], tm);
          float sc = __expf(mr[qi] - mn);
          mr[qi] = mn;
          lr[qi] *= sc;
          float scb[4];
#pragma unroll
          for (int r = 0; r < 4; ++r) scb[r] = __shfl(sc, lk * 4 + r);
#pragma unroll
          for (int dt = 0; dt < 8; ++dt)
#pragma unroll
            for (int r = 0; r < 4; ++r) oa[qi][dt][r] *= scb[r];
        }
        float ts = 0.f;
#pragma unroll
        for (int ktc = 0; ktc < 4; ++ktc)
#pragma unroll
          for (int r = 0; r < 4; ++r) {
            float e = __expf(p[ktc][r] - mn);
            p[ktc][r] = e;
            ts += e;
          }
        ts += __shfl_xor(ts, 16);
        ts += __shfl_xor(ts, 32);
        lr[qi] += ts;
        // pack P pairs (consecutive kv) and write b64 to swizzled per-wave LDS
        char* pq = pw + (qi * 16 + la) * 128;
#pragma unroll
        for (int ktc = 0; ktc < 4; ++ktc) {
          uint2 gv;
          gv.x = pack2bf(p[ktc][0], p[ktc][1]);
          gv.y = pack2bf(p[ktc][2], p[ktc][3]);
          *(uint2*)(pq + ((32 * ktc + 8 * lk) ^ ((la & 7) << 4))) = gv;
        }
      }
      asm volatile("s_waitcnt lgkmcnt(0)" ::: "memory");

      // P fragments: pf[qi][ks] = P[q = qi*16+la][kv = ks*32 + lk*8 + i]
      bf16x8_t pf[2][2];
#pragma unroll
      for (int qi = 0; qi < 2; ++qi)
#pragma unroll
        for (int ks = 0; ks < 2; ++ks)
          pf[qi][ks] = __builtin_bit_cast(
              bf16x8_t, *(const ushort8*)(pw + (qi * 16 + la) * 128 +
                                          ((64 * ks + 16 * lk) ^ ((la & 7) << 4))));
      __builtin_amdgcn_s_setprio(1);
#pragma unroll
      for (int dt = 0; dt < 8; ++dt) {
        int d = dt * 16 + la;
#pragma unroll
        for (int ks = 0; ks < 2; ++ks) {
          bf16x8_t vf = __builtin_bit_cast(
              bf16x8_t, *(const ushort8*)(Vsb + d * 128 + ((((ks << 2) + lk) ^ (d & 7)) << 4)));
          oa[0][dt] = __builtin_amdgcn_mfma_f32_16x16x32_bf16(pf[0][ks], vf, oa[0][dt], 0, 0, 0);
          oa[1][dt] = __builtin_amdgcn_mfma_f32_16x16x32_bf16(pf[1][ks], vf, oa[1][dt], 0, 0, 0);
        }
      }
      __builtin_amdgcn_s_setprio(0);
    }

    __syncthreads();  // prefetched tile landed; all reads of cur done
    cur ^= 1;
  }

#pragma unroll
  for (int qi = 0; qi < 2; ++qi) {
    float inv = 1.f / lr[qi];
    float invb[4];
#pragma unroll
    for (int r = 0; r < 4; ++r) invb[r] = __shfl(inv, lk * 4 + r);
#pragma unroll
    for (int dt = 0; dt < 8; ++dt)
#pragma unroll
      for (int r = 0; r < 4; ++r)
        Ob[(size_t)(b * S + qw + qi * 16 + lk * 4 + r) * 2048 + h * 128 + dt * 16 + la] =
            f2bf(oa[qi][dt][r] * invb[r]);
  }
}

extern "C" void kernel_launch(void* const* d_in, const int* in_sizes, int n_in,
                              void* d_out, int out_size, void* d_ws, size_t ws_size,
                              hipStream_t stream) {
  const float* x = (const float*)d_in[0];
  const float* rc = (const float*)d_in[1];
  const float* rs = (const float*)d_in[2];
  const float* Wq = (const float*)d_in[3];
  const float* Wk = (const float*)d_in[4];
  const float* Wv = (const float*)d_in[5];
  const float* Wo = (const float*)d_in[6];
  float* out = (float*)d_out;

  const int B = 2, S = 2048, DM = 2048;
  const int M = B * S;  // 4096

  // workspace (bf16 elems): xb | QKV | WallT | WoT | (Vt in dead WallT rows)
  unsigned short* xb = (unsigned short*)d_ws;              // M x 2048      (16 MB)
  unsigned short* QKV = xb + (size_t)M * DM;               // M x 3072      (25.2 MB)
  unsigned short* WallT = QKV + (size_t)M * 3072;          // 3072 x 2048   (12.6 MB)
  unsigned short* WoT = WallT + (size_t)3072 * DM;         // 2048 x 2048   (8.4 MB)
  unsigned short* Vt = WallT + (size_t)2048 * 2048;        // 1024 x 2048 (4 MB, dead Wk/Wv rows)
  unsigned short* Ob = xb;                                 // alias (x dead after proj)

  dim3 blk(256);

  // unified prepass: weight transposes + x convert in one launch
  prep_k<<<dim3(14336), blk, 0, stream>>>(x, Wq, Wk, Wv, Wo, xb, WallT, WoT);

  // fused QKV projection + RoPE on cols < 2560 (Q and K regions)
  gemm_tn<true, true><<<dim3(3072 / 128, M / 128), blk, 0, stream>>>(xb, WallT, QKV, M, 3072, DM,
                                                                     rc, rs, 2560);

  transpose_v<<<dim3(S / 32, 4, B * 4), dim3(32, 8), 0, stream>>>(QKV, Vt);

  attn_mfma<<<dim3(S / 128, 16, B), dim3(256), 0, stream>>>(QKV, Vt, Ob);

  gemm_tn<false, false><<<dim3(DM / 128, M / 128), blk, 0, stream>>>(Ob, WoT, out, M, DM, DM,
                                                                     nullptr, nullptr, 0);
}